// Round 10
// baseline (1492.170 us; speedup 1.0000x reference)
//
#include <hip/hip_runtime.h>
#include <hip/hip_bf16.h>
#include <hip/hip_fp16.h>

#define N_NODES 10000
#define N_EDGES 640000
#define TOT_E   (N_EDGES + N_NODES)
#define HID     128
#define NEG_SLOPE 0.2f
#define N_ACT   4096

#define NBKT   250
#define NPB    40
#define P1_EPB 4096
#define P1_EPT 16
#define P1_BLOCKS 159
#define SLOTP  56
#define GEMM_BLOCKS (N_NODES / 16)       // 625
#define FUSE_BLOCKS (N_NODES / 8)        // 1250
#define SC_APB 16
#define SC_BLOCKS (N_ACT / SC_APB)       // 256
#define GRID_BLKS 512                    // 2 blocks/CU needed; LDS/VGPR allow 4 -> safe margin

// ---------------- shared-memory union (max 36 KB) ----------------
union LDSU {
    struct {                             // part1: 23.6 KB
        int hist[256];
        int lofs[256];
        int sc[256];
        unsigned stage[P1_EPB];
        unsigned char bkt_of[P1_EPB];
    } p1;
    struct {                             // part2: 17.6 KB
        unsigned ebuf[4096];
        int sc[256];
        int nhist[NPB];
        int bstart, cnt;
    } p2;
    struct {                             // gemm0: 32 KB
        float Wc[2][32 * HID];
    } g;
    struct {                             // fuse: 36 KB
        float hT[8][HID];
        float Wc[2][32 * HID];
    } f;
    struct {                             // score: 33.5 KB
        float featT[257][SC_APB + 1];
        float Wc[2][16 * HID];
    } s;
};

// ---------------- manual grid barrier (device-scope, cross-XCD safe) ----------------
__device__ __forceinline__ void grid_barrier(int* __restrict__ bar, int gen) {
    __syncthreads();                     // all block threads done with phase writes
    if (threadIdx.x == 0) {
        __threadfence();                 // release: write back this XCD's L2
        atomicAdd(&bar[gen], 1);         // device-scope arrive
        while (__hip_atomic_load(&bar[gen], __ATOMIC_ACQUIRE,
                                 __HIP_MEMORY_SCOPE_AGENT) < GRID_BLKS)
            __builtin_amdgcn_s_sleep(1);
        __threadfence();                 // acquire: invalidate stale L1/L2 lines
    }
    __syncthreads();
}

// ---------------- phase device functions (identical numerics to R8) ----------------

__device__ __forceinline__ void gemm0_block(int bid, LDSU& u,
                                            const float* __restrict__ A,
                                            const float* __restrict__ W,
                                            const float* __restrict__ avs,
                                            const float* __restrict__ avd,
                                            __half* __restrict__ z16,
                                            float* __restrict__ zs,
                                            float* __restrict__ zd) {
    int t = threadIdx.x;
    float4 wreg[4];
    {
        const float4* Wg = (const float4*)W;
#pragma unroll
        for (int i = 0; i < 4; i++) wreg[i] = Wg[t + 256 * i];
    }
    int tx = t & 31;
    int ty = t >> 5;
    int row0 = bid * 16 + ty * 2;
    float acc[2][4] = {{0.f}};
    float4 a_nxt[2];
#pragma unroll
    for (int r = 0; r < 2; r++) a_nxt[r] = *(const float4*)&A[(row0 + r) * HID];

    for (int c = 0; c < 4; c++) {
        float4* dstb = (float4*)u.g.Wc[c & 1];
#pragma unroll
        for (int i = 0; i < 4; i++) dstb[t + 256 * i] = wreg[i];
        __syncthreads();
        if (c + 1 < 4) {
            const float4* Wg = (const float4*)(W + (c + 1) * 32 * HID);
#pragma unroll
            for (int i = 0; i < 4; i++) wreg[i] = Wg[t + 256 * i];
        }
        const float* Wb = u.g.Wc[c & 1];
#pragma unroll
        for (int k8 = 0; k8 < 32; k8 += 4) {
            float a_cur[2][4];
#pragma unroll
            for (int r = 0; r < 2; r++) {
                a_cur[r][0] = a_nxt[r].x; a_cur[r][1] = a_nxt[r].y;
                a_cur[r][2] = a_nxt[r].z; a_cur[r][3] = a_nxt[r].w;
            }
            int kn = c * 32 + k8 + 4;
            if (kn < HID) {
#pragma unroll
                for (int r = 0; r < 2; r++)
                    a_nxt[r] = *(const float4*)&A[(row0 + r) * HID + kn];
            }
#pragma unroll
            for (int kk = 0; kk < 4; kk++) {
                float4 wv = *(const float4*)&Wb[(k8 + kk) * HID + tx * 4];
#pragma unroll
                for (int r = 0; r < 2; r++) {
                    acc[r][0] = fmaf(a_cur[r][kk], wv.x, acc[r][0]);
                    acc[r][1] = fmaf(a_cur[r][kk], wv.y, acc[r][1]);
                    acc[r][2] = fmaf(a_cur[r][kk], wv.z, acc[r][2]);
                    acc[r][3] = fmaf(a_cur[r][kk], wv.w, acc[r][3]);
                }
            }
        }
    }
    float4 asv = *(const float4*)&avs[tx * 4];
    float4 adv = *(const float4*)&avd[tx * 4];
#pragma unroll
    for (int r = 0; r < 2; r++) {
        int row = row0 + r;
        *(__half2*)&z16[row * HID + tx * 4]     = __floats2half2_rn(acc[r][0], acc[r][1]);
        *(__half2*)&z16[row * HID + tx * 4 + 2] = __floats2half2_rn(acc[r][2], acc[r][3]);
        float ps = acc[r][0] * asv.x + acc[r][1] * asv.y + acc[r][2] * asv.z + acc[r][3] * asv.w;
        float pd = acc[r][0] * adv.x + acc[r][1] * adv.y + acc[r][2] * adv.z + acc[r][3] * adv.w;
#pragma unroll
        for (int o = 1; o < 32; o <<= 1) {
            ps += __shfl_xor(ps, o, 64);
            pd += __shfl_xor(pd, o, 64);
        }
        if (tx == 0) { zs[row] = ps; zd[row] = pd; }
    }
    __syncthreads();
}

__device__ __forceinline__ void part1_block(int blk, LDSU& u,
                                            const int* __restrict__ ei,
                                            unsigned* __restrict__ bpart,
                                            int* __restrict__ bcnt) {
    int t = threadIdx.x;
    u.p1.hist[t] = 0;
    __syncthreads();

    unsigned pk[P1_EPT];
    int bk[P1_EPT];
    int e0 = blk * P1_EPB;
#pragma unroll
    for (int i = 0; i < P1_EPT; i++) {
        int e = e0 + i * 256 + t;
        if (e < TOT_E) {
            int src, dst;
            if (e < N_EDGES) { src = ei[e]; dst = ei[N_EDGES + e]; }
            else             { src = e - N_EDGES; dst = src; }
            pk[i] = ((unsigned)dst << 16) | (unsigned)src;
            bk[i] = dst / NPB;
            atomicAdd(&u.p1.hist[bk[i]], 1);
        } else bk[i] = -1;
    }
    __syncthreads();
    int v = u.p1.hist[t];
    u.p1.sc[t] = v;
    __syncthreads();
    for (int o = 1; o < 256; o <<= 1) {
        int uu = (t >= o) ? u.p1.sc[t - o] : 0;
        __syncthreads();
        u.p1.sc[t] += uu;
        __syncthreads();
    }
    u.p1.lofs[t] = u.p1.sc[t] - v;
    bcnt[blk * 256 + t] = v;
    u.p1.hist[t] = 0;
    __syncthreads();
#pragma unroll
    for (int i = 0; i < P1_EPT; i++) {
        if (bk[i] >= 0) {
            int p = atomicAdd(&u.p1.hist[bk[i]], 1);
            int slot = u.p1.lofs[bk[i]] + p;
            u.p1.stage[slot] = pk[i];
            u.p1.bkt_of[slot] = (unsigned char)bk[i];
        }
    }
    __syncthreads();
    int nv = min(P1_EPB, TOT_E - e0);
    for (int s = t; s < nv; s += 256) {
        int b = u.p1.bkt_of[s];
        bpart[b * (P1_BLOCKS * SLOTP) + blk * SLOTP + (s - u.p1.lofs[b])] = u.p1.stage[s];
    }
    __syncthreads();
}

__device__ __forceinline__ void part2_block(int b, LDSU& u,
                                            const unsigned* __restrict__ bpart,
                                            const int* __restrict__ bcnt,
                                            int* __restrict__ csr,
                                            int* __restrict__ offs) {
    int t = threadIdx.x;
    int tot = 0;
    if (t < NBKT)
        for (int blk = 0; blk < P1_BLOCKS; blk++) tot += bcnt[blk * 256 + t];
    u.p2.sc[t] = (t < NBKT) ? tot : 0;
    __syncthreads();
    for (int o = 1; o < 256; o <<= 1) {
        int uu = (t >= o) ? u.p2.sc[t - o] : 0;
        __syncthreads();
        u.p2.sc[t] += uu;
        __syncthreads();
    }
    if (t == b) { u.p2.bstart = u.p2.sc[t] - tot; u.p2.cnt = tot; }
    if (b == 0 && t == 255) offs[N_NODES] = u.p2.sc[255];
    __syncthreads();

    int L = (t < P1_BLOCKS) ? bcnt[t * 256 + b] : 0;
    u.p2.sc[t] = L;
    __syncthreads();
    for (int o = 1; o < 256; o <<= 1) {
        int uu = (t >= o) ? u.p2.sc[t - o] : 0;
        __syncthreads();
        u.p2.sc[t] += uu;
        __syncthreads();
    }
    int P = u.p2.sc[t] - L;
    if (t < NPB) u.p2.nhist[t] = 0;
    if (t < P1_BLOCKS && L > 0) {
        const unsigned* myrun = bpart + b * (P1_BLOCKS * SLOTP) + t * SLOTP;
        for (int i = 0; i < L; i++) u.p2.ebuf[P + i] = myrun[i];
    }
    __syncthreads();

    int cnt = u.p2.cnt;
    int n0 = b * NPB;
    for (int i = t; i < cnt; i += 256) atomicAdd(&u.p2.nhist[(u.p2.ebuf[i] >> 16) - n0], 1);
    __syncthreads();
    if (t < 64) {
        int v2 = (t < NPB) ? u.p2.nhist[t] : 0;
        int s2 = v2;
        for (int o = 1; o < 64; o <<= 1) {
            int uu = __shfl_up(s2, o, 64);
            if (t >= o) s2 += uu;
        }
        if (t < NPB) {
            int ofs = u.p2.bstart + s2 - v2;
            u.p2.nhist[t] = ofs;
            offs[n0 + t] = ofs;
        }
    }
    __syncthreads();
    for (int i = t; i < cnt; i += 256) {
        unsigned pk = u.p2.ebuf[i];
        int p = atomicAdd(&u.p2.nhist[(pk >> 16) - n0], 1);
        csr[p] = pk & 0xFFFF;
    }
    __syncthreads();
}

__device__ __forceinline__ void agg_node(const __half2* __restrict__ z2,
                                         const float* __restrict__ zsi, float zdn,
                                         const int* __restrict__ csr, int o0, int deg,
                                         int lane, float& accx, float& accy, float& denom) {
    for (int base = 0; base < deg; base += 64) {
        int j = base + lane;
        int sreg = 0;
        float ex = 0.f;
        if (j < deg) {
            int s = csr[o0 + j];
            sreg = s;
            float e = zsi[s] + zdn;
            e = e > 0.f ? e : NEG_SLOPE * e;
            ex = __expf(e);
        }
        int cnt = min(64, deg - base);
        int q = 0;
        for (; q + 16 <= cnt; q += 16) {
#pragma unroll
            for (int uu = 0; uu < 16; uu++) {
                int sq = __builtin_amdgcn_readlane(sreg, q + uu);
                float exq = __uint_as_float(
                    __builtin_amdgcn_readlane(__float_as_uint(ex), q + uu));
                denom += exq;
                float2 vf = __half22float2(z2[sq * 64]);
                accx = fmaf(exq, vf.x, accx);
                accy = fmaf(exq, vf.y, accy);
            }
        }
        for (; q < cnt; q++) {
            int sq = __builtin_amdgcn_readlane(sreg, q);
            float exq = __uint_as_float(
                __builtin_amdgcn_readlane(__float_as_uint(ex), q));
            denom += exq;
            float2 vf = __half22float2(z2[sq * 64]);
            accx = fmaf(exq, vf.x, accx);
            accy = fmaf(exq, vf.y, accy);
        }
    }
}

__device__ __forceinline__ void fuse_block(int bid, LDSU& u,
                                           const __half* __restrict__ z16i,
                                           const float* __restrict__ zsi,
                                           const float* __restrict__ zdi,
                                           const int* __restrict__ offs,
                                           const int* __restrict__ csr,
                                           const float* __restrict__ bprev,
                                           const float* __restrict__ W,
                                           const float* __restrict__ avs,
                                           const float* __restrict__ avd,
                                           __half* __restrict__ z16o,
                                           float* __restrict__ zso,
                                           float* __restrict__ zdo) {
    int t = threadIdx.x;
    int w = t >> 6, lane = t & 63;
    int n0 = bid * 8;
    float4 wreg[4];
    {
        const float4* Wg = (const float4*)W;
#pragma unroll
        for (int i = 0; i < 4; i++) wreg[i] = Wg[t + 256 * i];
    }
    const __half2* z2 = (const __half2*)z16i + lane;

    float2 bv = *(const float2*)&bprev[2 * lane];
#pragma unroll
    for (int i = 0; i < 2; i++) {
        int ln = w * 2 + i;
        int n = n0 + ln;
        int o0 = offs[n];
        int deg = offs[n + 1] - o0;
        float zdn = zdi[n];
        float accx = 0.f, accy = 0.f, denom = 0.f;
        agg_node(z2, zsi, zdn, csr, o0, deg, lane, accx, accy, denom);
        float inv = 1.0f / denom;
        float vx = accx * inv + bv.x;
        float vy = accy * inv + bv.y;
        float2 hv;
        hv.x = vx > 0.f ? vx : 0.f;
        hv.y = vy > 0.f ? vy : 0.f;
        *(float2*)&u.f.hT[ln][2 * lane] = hv;
    }

    int tx = t & 31, ty = t >> 5;
    float acc[4] = {0.f, 0.f, 0.f, 0.f};
    for (int c = 0; c < 4; c++) {
        float4* dstb = (float4*)u.f.Wc[c & 1];
#pragma unroll
        for (int i = 0; i < 4; i++) dstb[t + 256 * i] = wreg[i];
        __syncthreads();
        if (c + 1 < 4) {
            const float4* Wg = (const float4*)(W + (c + 1) * 32 * HID);
#pragma unroll
            for (int i = 0; i < 4; i++) wreg[i] = Wg[t + 256 * i];
        }
        const float* Wb = u.f.Wc[c & 1];
        const float* h0 = &u.f.hT[ty][c * 32];
#pragma unroll 8
        for (int kk = 0; kk < 32; kk++) {
            float f0 = h0[kk];
            float4 wv = *(const float4*)&Wb[kk * HID + tx * 4];
            acc[0] = fmaf(f0, wv.x, acc[0]);
            acc[1] = fmaf(f0, wv.y, acc[1]);
            acc[2] = fmaf(f0, wv.z, acc[2]);
            acc[3] = fmaf(f0, wv.w, acc[3]);
        }
    }
    float4 asv = *(const float4*)&avs[tx * 4];
    float4 adv = *(const float4*)&avd[tx * 4];
    int row = n0 + ty;
    *(__half2*)&z16o[row * HID + tx * 4]     = __floats2half2_rn(acc[0], acc[1]);
    *(__half2*)&z16o[row * HID + tx * 4 + 2] = __floats2half2_rn(acc[2], acc[3]);
    float ps = acc[0] * asv.x + acc[1] * asv.y + acc[2] * asv.z + acc[3] * asv.w;
    float pd = acc[0] * adv.x + acc[1] * adv.y + acc[2] * adv.z + acc[3] * adv.w;
#pragma unroll
    for (int o = 1; o < 32; o <<= 1) {
        ps += __shfl_xor(ps, o, 64);
        pd += __shfl_xor(pd, o, 64);
    }
    if (tx == 0) { zso[row] = ps; zdo[row] = pd; }
    __syncthreads();
}

__device__ __forceinline__ void agg8_block(int bid,
                                           const __half* __restrict__ z16,
                                           const float* __restrict__ zs,
                                           const float* __restrict__ zd,
                                           const int* __restrict__ offs,
                                           const int* __restrict__ csr,
                                           const float* __restrict__ b,
                                           float* __restrict__ hout) {
    int t = threadIdx.x;
    int w = t >> 6, lane = t & 63;
    const __half2* z2 = (const __half2*)z16 + lane;
    float2 bv = *(const float2*)&b[2 * lane];
#pragma unroll
    for (int i = 0; i < 2; i++) {
        int n = bid * 8 + w * 2 + i;
        int o0 = offs[n];
        int deg = offs[n + 1] - o0;
        float zdn = zd[n];
        float accx = 0.f, accy = 0.f, denom = 0.f;
        agg_node(z2, zs, zdn, csr, o0, deg, lane, accx, accy, denom);
        float inv = 1.0f / denom;
        float vx = accx * inv + bv.x;
        float vy = accy * inv + bv.y;
        float2 o;
        o.x = vx > 0.f ? vx : 0.f;
        o.y = vy > 0.f ? vy : 0.f;
        *(float2*)&hout[n * HID + 2 * lane] = o;
    }
}

__device__ __forceinline__ void score_block(int bid, LDSU& u,
                                            const float* __restrict__ h,
                                            const int* __restrict__ asrc,
                                            const int* __restrict__ adst,
                                            const int* __restrict__ atype,
                                            const float* __restrict__ W1,
                                            const float* __restrict__ b1,
                                            const float* __restrict__ W2,
                                            const float* __restrict__ b2,
                                            float* __restrict__ out) {
    int t = threadIdx.x;
    int a0 = bid * SC_APB;

    float4 wreg[2];
    {
        const float4* Wg = (const float4*)W1;
#pragma unroll
        for (int i = 0; i < 2; i++) wreg[i] = Wg[t + 256 * i];
    }
    for (int idx = t; idx < SC_APB * 128; idx += 256) {
        int a = idx >> 7, c = idx & 127;
        u.s.featT[c][a]       = h[asrc[a0 + a] * HID + c];
        u.s.featT[128 + c][a] = h[adst[a0 + a] * HID + c];
    }
    if (t < SC_APB) u.s.featT[256][t] = (float)atype[a0 + t];

    int cg = t & 31, ap = t >> 5;
    float4 bv = *(const float4*)&b1[cg * 4];
    float acc0[4] = {bv.x, bv.y, bv.z, bv.w};
    float acc1[4] = {bv.x, bv.y, bv.z, bv.w};

    for (int c = 0; c < 16; c++) {
        float4* dstb = (float4*)u.s.Wc[c & 1];
#pragma unroll
        for (int i = 0; i < 2; i++) dstb[t + 256 * i] = wreg[i];
        __syncthreads();
        if (c + 1 < 16) {
            const float4* Wg = (const float4*)(W1 + (c + 1) * 16 * HID);
#pragma unroll
            for (int i = 0; i < 2; i++) wreg[i] = Wg[t + 256 * i];
        }
        const float* Wb = u.s.Wc[c & 1];
        const float* fT = &u.s.featT[c * 16][0];
#pragma unroll 8
        for (int kk = 0; kk < 16; kk++) {
            float4 wv = *(const float4*)&Wb[kk * HID + cg * 4];
            float f0 = fT[kk * (SC_APB + 1) + ap * 2];
            float f1 = fT[kk * (SC_APB + 1) + ap * 2 + 1];
            acc0[0] = fmaf(f0, wv.x, acc0[0]);
            acc0[1] = fmaf(f0, wv.y, acc0[1]);
            acc0[2] = fmaf(f0, wv.z, acc0[2]);
            acc0[3] = fmaf(f0, wv.w, acc0[3]);
            acc1[0] = fmaf(f1, wv.x, acc1[0]);
            acc1[1] = fmaf(f1, wv.y, acc1[1]);
            acc1[2] = fmaf(f1, wv.z, acc1[2]);
            acc1[3] = fmaf(f1, wv.w, acc1[3]);
        }
    }
    {
        float4 wv = *(const float4*)&W1[256 * HID + cg * 4];
        float f0 = u.s.featT[256][ap * 2];
        float f1 = u.s.featT[256][ap * 2 + 1];
        acc0[0] = fmaf(f0, wv.x, acc0[0]); acc0[1] = fmaf(f0, wv.y, acc0[1]);
        acc0[2] = fmaf(f0, wv.z, acc0[2]); acc0[3] = fmaf(f0, wv.w, acc0[3]);
        acc1[0] = fmaf(f1, wv.x, acc1[0]); acc1[1] = fmaf(f1, wv.y, acc1[1]);
        acc1[2] = fmaf(f1, wv.z, acc1[2]); acc1[3] = fmaf(f1, wv.w, acc1[3]);
    }
    float4 w2v = *(const float4*)&W2[cg * 4];
    float v0 = 0.f, v1 = 0.f;
    v0 += (acc0[0] > 0.f ? acc0[0] : 0.f) * w2v.x;
    v0 += (acc0[1] > 0.f ? acc0[1] : 0.f) * w2v.y;
    v0 += (acc0[2] > 0.f ? acc0[2] : 0.f) * w2v.z;
    v0 += (acc0[3] > 0.f ? acc0[3] : 0.f) * w2v.w;
    v1 += (acc1[0] > 0.f ? acc1[0] : 0.f) * w2v.x;
    v1 += (acc1[1] > 0.f ? acc1[1] : 0.f) * w2v.y;
    v1 += (acc1[2] > 0.f ? acc1[2] : 0.f) * w2v.z;
    v1 += (acc1[3] > 0.f ? acc1[3] : 0.f) * w2v.w;
#pragma unroll
    for (int o = 1; o < 32; o <<= 1) {
        v0 += __shfl_xor(v0, o, 64);
        v1 += __shfl_xor(v1, o, 64);
    }
    if (cg == 0) {
        out[a0 + ap * 2]     = v0 + b2[0];
        out[a0 + ap * 2 + 1] = v1 + b2[0];
    }
    __syncthreads();
}

// ---------------- mega kernel (plain launch + manual grid barrier) ----------------

struct MegaArgs {
    const float* x; const int* ei;
    const int* asrc; const int* adst; const int* atype;
    const float* gW; const float* gas; const float* gad; const float* gb;
    const float* W1; const float* b1; const float* W2; const float* b2;
    float* out;
    __half* z16A; __half* z16B; float* h3;
    float* zsA; float* zdA; float* zsB; float* zdB;
    int* offs; int* csr; int* bcnt; unsigned* bpart;
    int* bar;
};

__global__ __launch_bounds__(256, 2) void mega_k(MegaArgs a) {
    __shared__ LDSU u;
    const int nb = GRID_BLKS;

    // Phase A: gemm0 (625) + part1 (159)
    for (int task = blockIdx.x; task < GEMM_BLOCKS + P1_BLOCKS; task += nb) {
        if (task < GEMM_BLOCKS)
            gemm0_block(task, u, a.x, a.gW, a.gas, a.gad, a.z16A, a.zsA, a.zdA);
        else
            part1_block(task - GEMM_BLOCKS, u, a.ei, a.bpart, a.bcnt);
    }
    grid_barrier(a.bar, 0);

    // Phase B: part2 (250)
    for (int task = blockIdx.x; task < NBKT; task += nb)
        part2_block(task, u, a.bpart, a.bcnt, a.csr, a.offs);
    grid_barrier(a.bar, 1);

    // Phase C: layer0 agg + layer1 gemm (1250)
    for (int task = blockIdx.x; task < FUSE_BLOCKS; task += nb)
        fuse_block(task, u, a.z16A, a.zsA, a.zdA, a.offs, a.csr, a.gb,
                   a.gW + 1 * HID * HID, a.gas + 1 * HID, a.gad + 1 * HID,
                   a.z16B, a.zsB, a.zdB);
    grid_barrier(a.bar, 2);

    // Phase D: layer1 agg + layer2 gemm (1250)
    for (int task = blockIdx.x; task < FUSE_BLOCKS; task += nb)
        fuse_block(task, u, a.z16B, a.zsB, a.zdB, a.offs, a.csr, a.gb + 1 * HID,
                   a.gW + 2 * HID * HID, a.gas + 2 * HID, a.gad + 2 * HID,
                   a.z16A, a.zsA, a.zdA);
    grid_barrier(a.bar, 3);

    // Phase E: layer2 agg -> h3 (1250)
    for (int task = blockIdx.x; task < FUSE_BLOCKS; task += nb)
        agg8_block(task, a.z16A, a.zsA, a.zdA, a.offs, a.csr, a.gb + 2 * HID, a.h3);
    grid_barrier(a.bar, 4);

    // Phase F: score (256)
    for (int task = blockIdx.x; task < SC_BLOCKS; task += nb)
        score_block(task, u, a.h3, a.asrc, a.adst, a.atype,
                    a.W1, a.b1, a.W2, a.b2, a.out);
}

// ---------------- launch ----------------

extern "C" void kernel_launch(void* const* d_in, const int* in_sizes, int n_in,
                              void* d_out, int out_size, void* d_ws, size_t ws_size,
                              hipStream_t stream) {
    MegaArgs a;
    a.x    = (const float*)d_in[0];
    a.ei   = (const int*)d_in[1];
    a.asrc = (const int*)d_in[2];
    a.adst = (const int*)d_in[3];
    a.atype= (const int*)d_in[4];
    a.gW   = (const float*)d_in[5];
    a.gas  = (const float*)d_in[6];
    a.gad  = (const float*)d_in[7];
    a.gb   = (const float*)d_in[8];
    a.W1   = (const float*)d_in[9];
    a.b1   = (const float*)d_in[10];
    a.W2   = (const float*)d_in[11];
    a.b2   = (const float*)d_in[12];
    a.out  = (float*)d_out;

    a.bar  = (int*)d_ws;                            // 16 ints (64 B), zeroed below
    a.z16A = (__half*)(a.bar + 16);
    a.z16B = a.z16A + N_NODES * HID;
    a.h3   = (float*)(a.z16B + N_NODES * HID);
    a.zsA  = a.h3 + N_NODES * HID;
    a.zdA  = a.zsA + N_NODES;
    a.zsB  = a.zdA + N_NODES;
    a.zdB  = a.zsB + N_NODES;
    a.offs = (int*)(a.zdB + N_NODES);
    a.csr  = a.offs + (N_NODES + 1);
    a.bcnt = a.csr + TOT_E;
    a.bpart= (unsigned*)(a.bcnt + P1_BLOCKS * 256);

    hipMemsetAsync(a.bar, 0, 64, stream);
    mega_k<<<GRID_BLKS, 256, 0, stream>>>(a);
}

// Round 11
// 244.010 us; speedup vs baseline: 6.1152x; 6.1152x over previous
//
#include <hip/hip_runtime.h>
#include <hip/hip_bf16.h>
#include <hip/hip_fp16.h>

#define N_NODES 10000
#define N_EDGES 640000
#define TOT_E   (N_EDGES + N_NODES)
#define HID     128
#define NEG_SLOPE 0.2f
#define N_ACT   4096

// ---- deterministic bucket counting-sort CSR build (no global atomics) ----
#define NBKT   250
#define NPB    40
#define P1_EPB 4096
#define P1_EPT 16
#define P1_BLOCKS 159
#define SLOTP  56

__global__ __launch_bounds__(256) void part1_k(const int* __restrict__ ei,
                                               unsigned* __restrict__ bpart,
                                               int* __restrict__ bcnt) {
    __shared__ int hist[256];
    __shared__ int lofs[256];
    __shared__ int sc[256];
    __shared__ unsigned stage[P1_EPB];
    __shared__ unsigned char bkt_of[P1_EPB];
    int t = threadIdx.x;
    hist[t] = 0;
    __syncthreads();

    unsigned pk[P1_EPT];
    int bk[P1_EPT];
    int e0 = blockIdx.x * P1_EPB;
#pragma unroll
    for (int i = 0; i < P1_EPT; i++) {
        int e = e0 + i * 256 + t;
        if (e < TOT_E) {
            int src, dst;
            if (e < N_EDGES) { src = ei[e]; dst = ei[N_EDGES + e]; }
            else             { src = e - N_EDGES; dst = src; }
            pk[i] = ((unsigned)dst << 16) | (unsigned)src;
            bk[i] = dst / NPB;
            atomicAdd(&hist[bk[i]], 1);
        } else bk[i] = -1;
    }
    __syncthreads();
    int v = hist[t];
    sc[t] = v;
    __syncthreads();
    for (int o = 1; o < 256; o <<= 1) {
        int u = (t >= o) ? sc[t - o] : 0;
        __syncthreads();
        sc[t] += u;
        __syncthreads();
    }
    lofs[t] = sc[t] - v;
    bcnt[blockIdx.x * 256 + t] = v;
    hist[t] = 0;
    __syncthreads();
#pragma unroll
    for (int i = 0; i < P1_EPT; i++) {
        if (bk[i] >= 0) {
            int p = atomicAdd(&hist[bk[i]], 1);
            int slot = lofs[bk[i]] + p;
            stage[slot] = pk[i];
            bkt_of[slot] = (unsigned char)bk[i];
        }
    }
    __syncthreads();
    int nv = min(P1_EPB, TOT_E - e0);
    for (int s = t; s < nv; s += 256) {
        int b = bkt_of[s];
        bpart[b * (P1_BLOCKS * SLOTP) + blockIdx.x * SLOTP + (s - lofs[b])] = stage[s];
    }
}

__global__ __launch_bounds__(256) void part2_k(const unsigned* __restrict__ bpart,
                                               const int* __restrict__ bcnt,
                                               int* __restrict__ csr,
                                               int* __restrict__ offs) {
    __shared__ unsigned ebuf[4096];
    __shared__ int sc[256];
    __shared__ int nhist[NPB];
    __shared__ int bstart_s, cnt_s;
    int b = blockIdx.x, t = threadIdx.x;

    int tot = 0;
    if (t < NBKT)
        for (int blk = 0; blk < P1_BLOCKS; blk++) tot += bcnt[blk * 256 + t];
    sc[t] = (t < NBKT) ? tot : 0;
    __syncthreads();
    for (int o = 1; o < 256; o <<= 1) {
        int u = (t >= o) ? sc[t - o] : 0;
        __syncthreads();
        sc[t] += u;
        __syncthreads();
    }
    if (t == b) { bstart_s = sc[t] - tot; cnt_s = tot; }
    if (b == 0 && t == 255) offs[N_NODES] = sc[255];
    __syncthreads();

    int L = (t < P1_BLOCKS) ? bcnt[t * 256 + b] : 0;
    sc[t] = L;
    __syncthreads();
    for (int o = 1; o < 256; o <<= 1) {
        int u = (t >= o) ? sc[t - o] : 0;
        __syncthreads();
        sc[t] += u;
        __syncthreads();
    }
    int P = sc[t] - L;
    if (t < NPB) nhist[t] = 0;
    if (t < P1_BLOCKS && L > 0) {
        const unsigned* myrun = bpart + b * (P1_BLOCKS * SLOTP) + t * SLOTP;
        for (int i = 0; i < L; i++) ebuf[P + i] = myrun[i];
    }
    __syncthreads();

    int cnt = cnt_s;
    int n0 = b * NPB;
    for (int i = t; i < cnt; i += 256) atomicAdd(&nhist[(ebuf[i] >> 16) - n0], 1);
    __syncthreads();
    if (t < 64) {
        int v2 = (t < NPB) ? nhist[t] : 0;
        int s2 = v2;
        for (int o = 1; o < 64; o <<= 1) {
            int u = __shfl_up(s2, o, 64);
            if (t >= o) s2 += u;
        }
        if (t < NPB) {
            int ofs = bstart_s + s2 - v2;
            nhist[t] = ofs;
            offs[n0 + t] = ofs;
        }
    }
    __syncthreads();
    for (int i = t; i < cnt; i += 256) {
        unsigned pk = ebuf[i];
        int p = atomicAdd(&nhist[(pk >> 16) - n0], 1);
        csr[p] = pk & 0xFFFF;
    }
}

// -------- per-wave edge aggregate core (readlane broadcast) --------
__device__ __forceinline__ void agg_node(const __half2* __restrict__ z2,
                                         const float* __restrict__ zsi, float zdn,
                                         const int* __restrict__ csr, int o0, int deg,
                                         int lane, float& accx, float& accy, float& denom) {
    for (int base = 0; base < deg; base += 64) {
        int j = base + lane;
        int sreg = 0;
        float ex = 0.f;
        if (j < deg) {
            int s = csr[o0 + j];
            sreg = s;
            float e = zsi[s] + zdn;
            e = e > 0.f ? e : NEG_SLOPE * e;
            ex = __expf(e);
        }
        int cnt = min(64, deg - base);
        int q = 0;
        for (; q + 8 <= cnt; q += 8) {
#pragma unroll
            for (int u = 0; u < 8; u++) {
                int sq = __builtin_amdgcn_readlane(sreg, q + u);
                float exq = __uint_as_float(
                    __builtin_amdgcn_readlane(__float_as_uint(ex), q + u));
                denom += exq;
                float2 vf = __half22float2(z2[sq * 64]);
                accx = fmaf(exq, vf.x, accx);
                accy = fmaf(exq, vf.y, accy);
            }
        }
        for (; q < cnt; q++) {
            int sq = __builtin_amdgcn_readlane(sreg, q);
            float exq = __uint_as_float(
                __builtin_amdgcn_readlane(__float_as_uint(ex), q));
            denom += exq;
            float2 vf = __half22float2(z2[sq * 64]);
            accx = fmaf(exq, vf.x, accx);
            accy = fmaf(exq, vf.y, accy);
        }
    }
}

// -------- gemm0: z16 = fp16(x@W), zs, zd — dbuf W (32 KB) + prefetched A stream --------

__global__ __launch_bounds__(256) void gemm_k(const float* __restrict__ A,
                                              const float* __restrict__ W,
                                              const float* __restrict__ avs,
                                              const float* __restrict__ avd,
                                              __half* __restrict__ z16,
                                              float* __restrict__ zs,
                                              float* __restrict__ zd) {
    __shared__ float Wc[2][32 * HID];
    int t = threadIdx.x;
    float4 wreg[4];
    {
        const float4* Wg = (const float4*)W;
#pragma unroll
        for (int i = 0; i < 4; i++) wreg[i] = Wg[t + 256 * i];
    }
    int tx = t & 31;
    int ty = t >> 5;
    int row0 = blockIdx.x * 32 + ty * 4;
    float acc[4][4] = {{0.f}};
    float4 a_nxt[4];
#pragma unroll
    for (int r = 0; r < 4; r++) {
        int row = row0 + r;
        a_nxt[r] = (row < N_NODES) ? *(const float4*)&A[row * HID]
                                   : make_float4(0.f, 0.f, 0.f, 0.f);
    }
    for (int c = 0; c < 4; c++) {
        float4* dstb = (float4*)Wc[c & 1];
#pragma unroll
        for (int i = 0; i < 4; i++) dstb[t + 256 * i] = wreg[i];
        __syncthreads();
        if (c + 1 < 4) {
            const float4* Wg = (const float4*)(W + (c + 1) * 32 * HID);
#pragma unroll
            for (int i = 0; i < 4; i++) wreg[i] = Wg[t + 256 * i];
        }
        const float* Wb = Wc[c & 1];
#pragma unroll
        for (int k8 = 0; k8 < 32; k8 += 4) {
            float a_cur[4][4];
#pragma unroll
            for (int r = 0; r < 4; r++) {
                a_cur[r][0] = a_nxt[r].x; a_cur[r][1] = a_nxt[r].y;
                a_cur[r][2] = a_nxt[r].z; a_cur[r][3] = a_nxt[r].w;
            }
            int kn = c * 32 + k8 + 4;
            if (kn < HID) {
#pragma unroll
                for (int r = 0; r < 4; r++) {
                    int row = row0 + r;
                    a_nxt[r] = (row < N_NODES) ? *(const float4*)&A[row * HID + kn]
                                               : make_float4(0.f, 0.f, 0.f, 0.f);
                }
            }
#pragma unroll
            for (int kk = 0; kk < 4; kk++) {
                float4 wv = *(const float4*)&Wb[(k8 + kk) * HID + tx * 4];
#pragma unroll
                for (int r = 0; r < 4; r++) {
                    acc[r][0] = fmaf(a_cur[r][kk], wv.x, acc[r][0]);
                    acc[r][1] = fmaf(a_cur[r][kk], wv.y, acc[r][1]);
                    acc[r][2] = fmaf(a_cur[r][kk], wv.z, acc[r][2]);
                    acc[r][3] = fmaf(a_cur[r][kk], wv.w, acc[r][3]);
                }
            }
        }
    }
    float4 asv = *(const float4*)&avs[tx * 4];
    float4 adv = *(const float4*)&avd[tx * 4];
#pragma unroll
    for (int r = 0; r < 4; r++) {
        int row = row0 + r;
        if (row < N_NODES) {
            *(__half2*)&z16[row * HID + tx * 4]     = __floats2half2_rn(acc[r][0], acc[r][1]);
            *(__half2*)&z16[row * HID + tx * 4 + 2] = __floats2half2_rn(acc[r][2], acc[r][3]);
        }
        float ps = acc[r][0] * asv.x + acc[r][1] * asv.y + acc[r][2] * asv.z + acc[r][3] * asv.w;
        float pd = acc[r][0] * adv.x + acc[r][1] * adv.y + acc[r][2] * adv.z + acc[r][3] * adv.w;
#pragma unroll
        for (int o = 1; o < 32; o <<= 1) {
            ps += __shfl_xor(ps, o, 64);
            pd += __shfl_xor(pd, o, 64);
        }
        if (tx == 0 && row < N_NODES) { zs[row] = ps; zd[row] = pd; }
    }
}

// -------- fused: agg(l) -> hT in LDS -> gemm(l+1), dbuf W; W chunk0 loads fly during agg --------

__global__ __launch_bounds__(256, 4) void fuse_k(const __half* __restrict__ z16i,
                                                 const float* __restrict__ zsi,
                                                 const float* __restrict__ zdi,
                                                 const int* __restrict__ offs,
                                                 const int* __restrict__ csr,
                                                 const float* __restrict__ bprev,
                                                 const float* __restrict__ W,
                                                 const float* __restrict__ avs,
                                                 const float* __restrict__ avd,
                                                 __half* __restrict__ z16o,
                                                 float* __restrict__ zso,
                                                 float* __restrict__ zdo) {
    __shared__ float hT[16][HID];        // 8 KB
    __shared__ float Wc[2][32 * HID];    // 32 KB
    int t = threadIdx.x;
    int w = t >> 6, lane = t & 63;
    int n0 = blockIdx.x * 16;
    float4 wreg[4];
    {
        const float4* Wg = (const float4*)W;
#pragma unroll
        for (int i = 0; i < 4; i++) wreg[i] = Wg[t + 256 * i];
    }
    const __half2* z2 = (const __half2*)z16i + lane;

    float2 bv = *(const float2*)&bprev[2 * lane];
#pragma unroll
    for (int i = 0; i < 4; i++) {
        int ln = w * 4 + i;
        int n = n0 + ln;
        int o0 = offs[n];
        int deg = offs[n + 1] - o0;
        float zdn = zdi[n];
        float accx = 0.f, accy = 0.f, denom = 0.f;
        agg_node(z2, zsi, zdn, csr, o0, deg, lane, accx, accy, denom);
        float inv = 1.0f / denom;
        float vx = accx * inv + bv.x;
        float vy = accy * inv + bv.y;
        float2 hv;
        hv.x = vx > 0.f ? vx : 0.f;
        hv.y = vy > 0.f ? vy : 0.f;
        *(float2*)&hT[ln][2 * lane] = hv;
    }

    int tx = t & 31, ty = t >> 5;
    int r0 = ty * 2, r1 = ty * 2 + 1;
    float acc[2][4] = {{0.f}};
    for (int c = 0; c < 4; c++) {
        float4* dstb = (float4*)Wc[c & 1];
#pragma unroll
        for (int i = 0; i < 4; i++) dstb[t + 256 * i] = wreg[i];
        __syncthreads();                 // publishes Wc chunk c (and hT on c==0)
        if (c + 1 < 4) {
            const float4* Wg = (const float4*)(W + (c + 1) * 32 * HID);
#pragma unroll
            for (int i = 0; i < 4; i++) wreg[i] = Wg[t + 256 * i];
        }
        const float* Wb = Wc[c & 1];
        const float* h0 = &hT[r0][c * 32];
        const float* h1 = &hT[r1][c * 32];
#pragma unroll 8
        for (int kk = 0; kk < 32; kk++) {
            float f0 = h0[kk], f1 = h1[kk];
            float4 wv = *(const float4*)&Wb[kk * HID + tx * 4];
            acc[0][0] = fmaf(f0, wv.x, acc[0][0]);
            acc[0][1] = fmaf(f0, wv.y, acc[0][1]);
            acc[0][2] = fmaf(f0, wv.z, acc[0][2]);
            acc[0][3] = fmaf(f0, wv.w, acc[0][3]);
            acc[1][0] = fmaf(f1, wv.x, acc[1][0]);
            acc[1][1] = fmaf(f1, wv.y, acc[1][1]);
            acc[1][2] = fmaf(f1, wv.z, acc[1][2]);
            acc[1][3] = fmaf(f1, wv.w, acc[1][3]);
        }
    }
    float4 asv = *(const float4*)&avs[tx * 4];
    float4 adv = *(const float4*)&avd[tx * 4];
#pragma unroll
    for (int r = 0; r < 2; r++) {
        int row = n0 + (r ? r1 : r0);
        *(__half2*)&z16o[row * HID + tx * 4]     = __floats2half2_rn(acc[r][0], acc[r][1]);
        *(__half2*)&z16o[row * HID + tx * 4 + 2] = __floats2half2_rn(acc[r][2], acc[r][3]);
        float ps = acc[r][0] * asv.x + acc[r][1] * asv.y + acc[r][2] * asv.z + acc[r][3] * asv.w;
        float pd = acc[r][0] * adv.x + acc[r][1] * adv.y + acc[r][2] * adv.z + acc[r][3] * adv.w;
#pragma unroll
        for (int o = 1; o < 32; o <<= 1) {
            ps += __shfl_xor(ps, o, 64);
            pd += __shfl_xor(pd, o, 64);
        }
        if (tx == 0) { zso[row] = ps; zdo[row] = pd; }
    }
}

// -------- final-layer aggregate -> h3 --------

__global__ __launch_bounds__(256) void agg_k(const __half* __restrict__ z16,
                                             const float* __restrict__ zs,
                                             const float* __restrict__ zd,
                                             const int* __restrict__ offs,
                                             const int* __restrict__ csr,
                                             const float* __restrict__ b,
                                             float* __restrict__ hout) {
    int t = threadIdx.x;
    int w = t >> 6, lane = t & 63;
    int n = blockIdx.x * 4 + w;
    if (n >= N_NODES) return;
    int o0 = offs[n];
    int deg = offs[n + 1] - o0;
    float zdn = zd[n];
    const __half2* z2 = (const __half2*)z16 + lane;
    float accx = 0.f, accy = 0.f, denom = 0.f;
    agg_node(z2, zs, zdn, csr, o0, deg, lane, accx, accy, denom);
    float inv = 1.0f / denom;
    float2 bv = *(const float2*)&b[2 * lane];
    float vx = accx * inv + bv.x;
    float vy = accy * inv + bv.y;
    float2 o;
    o.x = vx > 0.f ? vx : 0.f;
    o.y = vy > 0.f ? vy : 0.f;
    *(float2*)&hout[n * HID + 2 * lane] = o;
}

// -------- action scoring: tiled GEMM, 16 actions/block × 256 blocks, dbuf W1 --------

#define SC_APB 16

__global__ __launch_bounds__(256) void score_k(const float* __restrict__ h,
                                               const int* __restrict__ asrc,
                                               const int* __restrict__ adst,
                                               const int* __restrict__ atype,
                                               const float* __restrict__ W1,
                                               const float* __restrict__ b1,
                                               const float* __restrict__ W2,
                                               const float* __restrict__ b2,
                                               float* __restrict__ out) {
    __shared__ float featT[257][SC_APB + 1];   // [k][action], padded
    __shared__ float Wc[2][32 * HID];          // 32 KB
    int t = threadIdx.x;
    int a0 = blockIdx.x * SC_APB;

    float4 wreg[4];
    {
        const float4* Wg = (const float4*)W1;
#pragma unroll
        for (int i = 0; i < 4; i++) wreg[i] = Wg[t + 256 * i];
    }
    for (int idx = t; idx < SC_APB * 128; idx += 256) {
        int a = idx >> 7, c = idx & 127;
        featT[c][a]       = h[asrc[a0 + a] * HID + c];
        featT[128 + c][a] = h[adst[a0 + a] * HID + c];
    }
    if (t < SC_APB) featT[256][t] = (float)atype[a0 + t];

    int cg = t & 31, ap = t >> 5;
    float4 bv = *(const float4*)&b1[cg * 4];
    float acc0[4] = {bv.x, bv.y, bv.z, bv.w};
    float acc1[4] = {bv.x, bv.y, bv.z, bv.w};

    for (int c = 0; c < 8; c++) {
        float4* dstb = (float4*)Wc[c & 1];
#pragma unroll
        for (int i = 0; i < 4; i++) dstb[t + 256 * i] = wreg[i];
        __syncthreads();
        if (c + 1 < 8) {
            const float4* Wg = (const float4*)(W1 + (c + 1) * 32 * HID);
#pragma unroll
            for (int i = 0; i < 4; i++) wreg[i] = Wg[t + 256 * i];
        }
        const float* Wb = Wc[c & 1];
        const float* fT = &featT[c * 32][0];
#pragma unroll 8
        for (int kk = 0; kk < 32; kk++) {
            float4 wv = *(const float4*)&Wb[kk * HID + cg * 4];
            float f0 = fT[kk * (SC_APB + 1) + ap * 2];
            float f1 = fT[kk * (SC_APB + 1) + ap * 2 + 1];
            acc0[0] = fmaf(f0, wv.x, acc0[0]);
            acc0[1] = fmaf(f0, wv.y, acc0[1]);
            acc0[2] = fmaf(f0, wv.z, acc0[2]);
            acc0[3] = fmaf(f0, wv.w, acc0[3]);
            acc1[0] = fmaf(f1, wv.x, acc1[0]);
            acc1[1] = fmaf(f1, wv.y, acc1[1]);
            acc1[2] = fmaf(f1, wv.z, acc1[2]);
            acc1[3] = fmaf(f1, wv.w, acc1[3]);
        }
    }
    {
        float4 wv = *(const float4*)&W1[256 * HID + cg * 4];
        float f0 = featT[256][ap * 2];
        float f1 = featT[256][ap * 2 + 1];
        acc0[0] = fmaf(f0, wv.x, acc0[0]); acc0[1] = fmaf(f0, wv.y, acc0[1]);
        acc0[2] = fmaf(f0, wv.z, acc0[2]); acc0[3] = fmaf(f0, wv.w, acc0[3]);
        acc1[0] = fmaf(f1, wv.x, acc1[0]); acc1[1] = fmaf(f1, wv.y, acc1[1]);
        acc1[2] = fmaf(f1, wv.z, acc1[2]); acc1[3] = fmaf(f1, wv.w, acc1[3]);
    }
    float4 w2v = *(const float4*)&W2[cg * 4];
    float v0 = 0.f, v1 = 0.f;
    v0 += (acc0[0] > 0.f ? acc0[0] : 0.f) * w2v.x;
    v0 += (acc0[1] > 0.f ? acc0[1] : 0.f) * w2v.y;
    v0 += (acc0[2] > 0.f ? acc0[2] : 0.f) * w2v.z;
    v0 += (acc0[3] > 0.f ? acc0[3] : 0.f) * w2v.w;
    v1 += (acc1[0] > 0.f ? acc1[0] : 0.f) * w2v.x;
    v1 += (acc1[1] > 0.f ? acc1[1] : 0.f) * w2v.y;
    v1 += (acc1[2] > 0.f ? acc1[2] : 0.f) * w2v.z;
    v1 += (acc1[3] > 0.f ? acc1[3] : 0.f) * w2v.w;
#pragma unroll
    for (int o = 1; o < 32; o <<= 1) {
        v0 += __shfl_xor(v0, o, 64);
        v1 += __shfl_xor(v1, o, 64);
    }
    if (cg == 0) {
        out[a0 + ap * 2]     = v0 + b2[0];
        out[a0 + ap * 2 + 1] = v1 + b2[0];
    }
}

// ---------------- launch ----------------

extern "C" void kernel_launch(void* const* d_in, const int* in_sizes, int n_in,
                              void* d_out, int out_size, void* d_ws, size_t ws_size,
                              hipStream_t stream) {
    const float* x   = (const float*)d_in[0];
    const int* ei    = (const int*)d_in[1];
    const int* asrc  = (const int*)d_in[2];
    const int* adst  = (const int*)d_in[3];
    const int* atype = (const int*)d_in[4];
    const float* gW  = (const float*)d_in[5];
    const float* gas = (const float*)d_in[6];
    const float* gad = (const float*)d_in[7];
    const float* gb  = (const float*)d_in[8];
    const float* W1  = (const float*)d_in[9];
    const float* b1  = (const float*)d_in[10];
    const float* W2  = (const float*)d_in[11];
    const float* b2  = (const float*)d_in[12];
    float* out = (float*)d_out;

    __half* z16A = (__half*)d_ws;
    __half* z16B = z16A + N_NODES * HID;
    float* h3   = (float*)(z16B + N_NODES * HID);
    float* zsA  = h3 + N_NODES * HID;
    float* zdA  = zsA + N_NODES;
    float* zsB  = zdA + N_NODES;
    float* zdB  = zsB + N_NODES;
    int* offs   = (int*)(zdB + N_NODES);
    int* csr    = offs + (N_NODES + 1);
    int* bcnt   = csr + TOT_E;
    unsigned* bpart = (unsigned*)(bcnt + P1_BLOCKS * 256);

    part1_k<<<P1_BLOCKS, 256, 0, stream>>>(ei, bpart, bcnt);
    part2_k<<<NBKT, 256, 0, stream>>>(bpart, bcnt, csr, offs);

    gemm_k<<<(N_NODES + 31) / 32, 256, 0, stream>>>(x, gW, gas, gad, z16A, zsA, zdA);
    fuse_k<<<N_NODES / 16, 256, 0, stream>>>(z16A, zsA, zdA, offs, csr, gb,
                                             gW + 1 * HID * HID, gas + 1 * HID, gad + 1 * HID,
                                             z16B, zsB, zdB);
    fuse_k<<<N_NODES / 16, 256, 0, stream>>>(z16B, zsB, zdB, offs, csr, gb + 1 * HID,
                                             gW + 2 * HID * HID, gas + 2 * HID, gad + 2 * HID,
                                             z16A, zsA, zdA);
    agg_k<<<(N_NODES + 3) / 4, 256, 0, stream>>>(z16A, zsA, zdA, offs, csr,
                                                 gb + 2 * HID, h3);
    score_k<<<N_ACT / SC_APB, 256, 0, stream>>>(h3, asrc, adst, atype,
                                                W1, b1, W2, b2, out);
}